// Round 8
// baseline (137.363 us; speedup 1.0000x reference)
//
#include <hip/hip_runtime.h>

// Problem constants (from reference: shape (32,1,512,512) fp32)
#define BATCH 32
#define H 512
#define W 512
#define N_TOT (BATCH * H * W)          // 8388608
#define SLAB 16                        // rows per block
#define NBLOCKS (BATCH * H / SLAB)     // 1024
#define RING 6                         // LDS ring slots (row-triples)
#define TRIPF (3 * W)                  // 1536 floats = 6 KB per triple
#define WS_FLOATS NBLOCKS

// R8: sequential-stream LDS ring with COUNTED vmcnt (T3+T4 discipline).
// Model fitted across R2/R4/R5/R7: per-CU concurrent-miss cap (~50-80
// lines) x ~900cy loaded HBM latency caps every register-window variant at
// ~3 TB/s; m13's 6.3 TB/s copy wins via sequential streams (DRAM row-buffer
// hits ~halve latency). So: read each byte ONCE (kill the 3x vertical
// re-read; 18/16 overfetch only), keep each block's 3 image streams
// strictly sequential, and never drain vmcnt to 0 in the loop (R4's
// __syncthreads drained per step -> 58us; m218: counted-vs-drain0 +38-73%).
// Structure: block = 16-row slab, 2 px/thread (256 thr = full 512-px row);
// 6-slot ring of 6KB row-triples (A,B,F rows); step p: stage triple p+4
// (3-deep prefetch ~2 compute phases of slack), per-wave counted vmcnt
// (waves 0-1 issue 2 loads/step -> vmcnt(4); waves 2-3 issue 1 -> vmcnt(2)),
// raw s_barrier (no drain), ds_read only the NEW row's 4-col window
// (stride 8B = 2-way bank alias = free), carry rows y-1,y in registers
// (36 floats; R4-style macros, no address-taken arrays -> no spill).
// OOB rows: stage clamped (keeps vmcnt counts uniform, L2-hot), zero the
// register window at read time (= reference zero padding).
// Kept: XCD-bijective swizzle (contiguous slabs per XCD), per-block partial
// + 1-block finish (no atomics). Harness dur_us includes ~83us of 268MB
// re-poison fills; only kernel time is ours.

#define GAS(p) ((__attribute__((address_space(1))) void*)(p))
#define LAS(p) ((__attribute__((address_space(3))) void*)(p))

template <bool USE_PARTIALS>
__global__ __launch_bounds__(256)
void fusion_loss_kernel(const float* __restrict__ A,
                        const float* __restrict__ B,
                        const float* __restrict__ F,
                        const int* __restrict__ scheme_arr,
                        float* __restrict__ sink)   // partials[] or out scalar
{
    __shared__ float sh[RING * TRIPF];  // 36 KB ring
    __shared__ float red[4];

    const int t    = threadIdx.x;
    const int lane = t & 63;
    const int ty   = t >> 6;

    // XCD-bijective swizzle (1024 % 8 == 0): each XCD owns 128 consecutive
    // slabs -> slab-boundary rows are same-XCD L2 hits.
    const int bid = blockIdx.x;
    const int lb  = (bid & 7) * (NBLOCKS / 8) + (bid >> 3);

    const int b    = lb >> 5;            // batch (32 slabs per image)
    const int y0   = (lb & 31) << 4;     // first output row of the slab
    const int base = b * (H * W);
    const int scheme = scheme_arr[b];

    // staging assignment (wave-uniform): triple = [A row | B row | F row],
    // each row = 2 KB = 2 x (64 lanes x 16 B).
    //   wave 0: A half0 + F half0   wave 1: A half1 + F half1
    //   wave 2: B half0             wave 3: B half1
    const int   im0  = ty >> 1;                   // 0,0,1,1 -> A,A,B,B
    const int   hf0  = ty & 1;
    const float* img0 = (im0 == 0) ? A : B;
    const bool  two  = (ty < 2);                  // waves 0,1 also stage F
    const int   hf1  = ty;                        // valid when two

    // triple T <-> input row y0-1+T, T in [0,19]; slot = T % RING.
    // OOB rows stage CLAMPED (uniform vmcnt counts; window zeroed at read).
#define STAGE(T_) do {                                                      \
    int y_ = y0 - 1 + (T_);                                                 \
    y_ = y_ < 0 ? 0 : (y_ > H - 1 ? H - 1 : y_);                            \
    float* d_ = sh + ((T_) % RING) * TRIPF;                                 \
    const float* s0_ = img0 + base + y_ * W + (hf0 << 8) + (lane << 2);     \
    __builtin_amdgcn_global_load_lds(GAS(s0_),                              \
        LAS(d_ + im0 * W + (hf0 << 8)), 16, 0, 0);                          \
    if (two) {                                                              \
        const float* s1_ = F + base + y_ * W + (hf1 << 8) + (lane << 2);    \
        __builtin_amdgcn_global_load_lds(GAS(s1_),                          \
            LAS(d_ + 2 * W + (hf1 << 8)), 16, 0, 0);                        \
    }                                                                       \
} while (0)

    // counted wait: my own oldest stage-call landed; 2 newest stay in
    // flight (never vmcnt(0) in the loop -- the whole point).
#define VWAIT() do {                                                        \
    if (two) asm volatile("s_waitcnt vmcnt(4)" ::: "memory");               \
    else     asm volatile("s_waitcnt vmcnt(2)" ::: "memory");               \
} while (0)

#define BAR() do {                                                          \
    __builtin_amdgcn_s_barrier();                                           \
    __builtin_amdgcn_sched_barrier(0);                                      \
} while (0)

    // per-thread window geometry: 2 px at cols c0, c0+1
    const int  c0 = t << 1;
    const bool eL = (t == 0), eR = (t == 255);
    const int  li = eL ? 0 : c0 - 1;      // in-bounds addr, masked below
    const int  ri = eR ? (W - 1) : c0 + 2;

    // LOADP: w_[im][0..3] = triple T_ row cols c0-1..c0+2; v_=false -> zeros
#define LOADP(w_, T_, v_) do {                                              \
    const float* lp_ = sh + ((T_) % RING) * TRIPF;                          \
    _Pragma("unroll")                                                       \
    for (int im_ = 0; im_ < 3; ++im_) {                                     \
        const float* rp_ = lp_ + im_ * W;                                   \
        const float2 cc_ = *reinterpret_cast<const float2*>(rp_ + c0);      \
        float l_ = rp_[li], r_ = rp_[ri];                                   \
        if (eL) l_ = 0.f;                                                   \
        if (eR) r_ = 0.f;                                                   \
        w_[im_][0] = (v_) ? l_    : 0.f;                                    \
        w_[im_][1] = (v_) ? cc_.x : 0.f;                                    \
        w_[im_][2] = (v_) ? cc_.y : 0.f;                                    \
        w_[im_][3] = (v_) ? r_    : 0.f;                                    \
    }                                                                       \
} while (0)

    float wm[3][4], wc[3][4], wp[3][4];
    float acc = 0.f;

    // separable sobel (s = m+2c+p col sums, d = m-p) + l_loss, 2 px
#define COMPUTE() do {                                                      \
    float sA0, sA1;                                                         \
    _Pragma("unroll")                                                       \
    for (int im_ = 0; im_ < 3; ++im_) {                                     \
        float s_0 = wm[im_][0] + 2.f * wc[im_][0] + wp[im_][0];             \
        float s_1 = wm[im_][1] + 2.f * wc[im_][1] + wp[im_][1];             \
        float s_2 = wm[im_][2] + 2.f * wc[im_][2] + wp[im_][2];             \
        float s_3 = wm[im_][3] + 2.f * wc[im_][3] + wp[im_][3];             \
        float d_0 = wm[im_][0] - wp[im_][0];                                \
        float d_1 = wm[im_][1] - wp[im_][1];                                \
        float d_2 = wm[im_][2] - wp[im_][2];                                \
        float d_3 = wm[im_][3] - wp[im_][3];                                \
        const float o0 = fabsf(s_2 - s_0) + fabsf(d_0 + 2.f * d_1 + d_2);   \
        const float o1 = fabsf(s_3 - s_1) + fabsf(d_1 + 2.f * d_2 + d_3);   \
        if (im_ == 0)      { sA0 = o0; sA1 = o1; }                          \
        else if (im_ == 1) { sA0 = fmaxf(sA0, o0); sA1 = fmaxf(sA1, o1); }  \
        else               { acc += fabsf(o0 - sA0) + fabsf(o1 - sA1); }    \
    }                                                                       \
    {                                                                       \
        const float ab0 = (scheme == 0) ? 0.5f * (wc[0][1] + wc[1][1])      \
                        : (scheme == 1) ? fmaxf(wc[0][1], wc[1][1]) : 0.f;  \
        const float ab1 = (scheme == 0) ? 0.5f * (wc[0][2] + wc[1][2])      \
                        : (scheme == 1) ? fmaxf(wc[0][2], wc[1][2]) : 0.f;  \
        acc += fabsf(ab0 - wc[2][1]) + fabsf(ab1 - wc[2][2]);               \
    }                                                                       \
} while (0)

#define CARRY() do {                                                        \
    _Pragma("unroll")                                                       \
    for (int im_ = 0; im_ < 3; ++im_) {                                     \
        _Pragma("unroll")                                                   \
        for (int j_ = 0; j_ < 4; ++j_) {                                    \
            wm[im_][j_] = wc[im_][j_];                                      \
            wc[im_][j_] = wp[im_][j_];                                      \
        }                                                                   \
    }                                                                       \
} while (0)

    // ---- prologue: stage triples 0..3; wait 0,1 landed (2,3 in flight) ----
    STAGE(0); STAGE(1); STAGE(2); STAGE(3);
    VWAIT();
    BAR();
    LOADP(wm, 0, (y0 > 0));             // row y0-1 (zero row for slab 0)
    LOADP(wc, 1, true);                 // row y0

    // ---- step p: output row y0+p; m/c carried, p-row = triple p+2 ----
#pragma unroll
    for (int p = 0; p < SLAB; ++p) {
        STAGE(p + 4);                   // 3-deep prefetch; slot of triple
                                        // p-2 (last read step p-2: safe)
        VWAIT();                        // triple p+2 landed (mine)
        BAR();                          // everyone's triple p+2 landed
        if (p < SLAB - 1) LOADP(wp, p + 2, true);
        else              LOADP(wp, p + 2, (y0 + SLAB < H)); // img bottom
        COMPUTE();
        CARRY();
    }

#undef STAGE
#undef VWAIT
#undef BAR
#undef LOADP
#undef COMPUTE
#undef CARRY

    // ---- reduction: 64-lane shuffle, cross-wave via LDS, one plain store
    // per block (syncthreads drains the leftover staged loads too).
#pragma unroll
    for (int offp = 32; offp > 0; offp >>= 1)
        acc += __shfl_down(acc, offp, 64);
    __syncthreads();
    if (lane == 0) red[ty] = acc;
    __syncthreads();
    if (t == 0) {
        const float s = red[0] + red[1] + red[2] + red[3];
        if (USE_PARTIALS)
            sink[bid] = s;
        else
            atomicAdd(sink, s * (1.0f / (float)N_TOT)); // fallback path
    }
}

// 1-block finish: sum NBLOCKS=1024 partials (256 threads x 1 float4),
// scale by 1/N, write the scalar. Kernel boundary on the stream guarantees
// visibility of kernel1's plain stores.
__global__ __launch_bounds__(256)
void fusion_finish(const float* __restrict__ partials, float* __restrict__ out)
{
    __shared__ float red[4];
    const int t    = threadIdx.x;
    const int lane = t & 63;
    const int ty   = t >> 6;

    const float4 p = reinterpret_cast<const float4*>(partials)[t];
    float v = (p.x + p.y) + (p.z + p.w);
#pragma unroll
    for (int off = 32; off > 0; off >>= 1)
        v += __shfl_down(v, off, 64);
    if (lane == 0) red[ty] = v;
    __syncthreads();
    if (t == 0)
        out[0] = (red[0] + red[1] + red[2] + red[3]) * (1.0f / (float)N_TOT);
}

extern "C" void kernel_launch(void* const* d_in, const int* in_sizes, int n_in,
                              void* d_out, int out_size, void* d_ws, size_t ws_size,
                              hipStream_t stream)
{
    const float* A = (const float*)d_in[0];
    const float* B = (const float*)d_in[1];
    const float* F = (const float*)d_in[2];
    const int* scheme = (const int*)d_in[3];
    float* out = (float*)d_out;

    if (d_ws != nullptr && ws_size >= WS_FLOATS * sizeof(float)) {
        float* partials = (float*)d_ws;   // 4 KB, 16B-aligned
        fusion_loss_kernel<true><<<dim3(NBLOCKS), dim3(256), 0, stream>>>(
            A, B, F, scheme, partials);
        fusion_finish<<<dim3(1), dim3(256), 0, stream>>>(partials, out);
    } else {
        // Fallback: atomic path (d_out poisoned -> zero it).
        hipMemsetAsync(out, 0, sizeof(float), stream);
        fusion_loss_kernel<false><<<dim3(NBLOCKS), dim3(256), 0, stream>>>(
            A, B, F, scheme, out);
    }
}

// Round 9
// 128.704 us; speedup vs baseline: 1.0673x; 1.0673x over previous
//
#include <hip/hip_runtime.h>

// Problem constants (from reference: shape (32,1,512,512) fp32)
#define BATCH 32
#define H 512
#define W 512
#define N_TOT (BATCH * H * W)          // 8388608
#define PAIRS_TOTAL (BATCH * H / 2)    // 8192 row-pairs
#define NBLOCKS (PAIRS_TOTAL / 4)      // 2048 blocks x 4 waves = 1 pair/wave
#define WS_FLOATS NBLOCKS

// R9: row-pair waves -- attack loads-per-pixel, keep the proven regime.
// Cross-round model: every register-window variant moves ~1.5-2.25
// loads/px and caps at ~3 TB/s effective; LDS rings (R4 58us, R8 44us)
// serialize on stage/barrier chains. R5 (full-row waves, 2.25 loads/px,
// (256,4)=VGPR 128, 4 waves/SIMD) = best ~33us kernel. This round halves
// the vertical redundancy: wave = TWO consecutive output rows {y,y+1}
// from FOUR loaded rows y-1..y+2 per image -> 1.5 loads/px (x0.67), L2
// vertical amplification 3x->2x, shfl halos per output row 6->4.
// Phased per image (sobel A -> sobel B -> l_loss+sobel F), NO
// sched_barriers (R7's regression: blocking load-hoisting entirely;
// with the 128-reg cap the compiler hoists exactly as much as fits --
// the R5 behavior that worked). Kept: 8 px/lane full-width rows, shfl
// column halos with lane-edge zero pad (= image edge), zero syncthreads
// in the hot path, XCD-bijective swizzle (2048%8==0), per-block partial
// store + 1-block finish (no atomics). Harness dur_us includes ~83us of
// 268MB re-poison fills; only kernel time is ours.

template <bool USE_PARTIALS>
__global__ __launch_bounds__(256, 4)
void fusion_loss_kernel(const float* __restrict__ A,
                        const float* __restrict__ B,
                        const float* __restrict__ F,
                        const int* __restrict__ scheme_arr,
                        float* __restrict__ sink)   // partials[] or out scalar
{
    __shared__ float red[4];

    const int t    = threadIdx.x;
    const int lane = t & 63;
    const int ty   = t >> 6;

    // XCD-bijective swizzle: each XCD owns 256 consecutive logical blocks
    // (2048 contiguous rows) -> vertical halo re-reads are same-XCD L2 hits.
    const int bid = blockIdx.x;
    const int lb  = (bid & 7) * (NBLOCKS / 8) + (bid >> 3);

    const int gp  = (lb << 2) | ty;       // global row-pair 0..8191
    const int gy  = gp << 1;              // first output row (even)
    const int b   = gy >> 9;              // batch (block = 8 aligned rows,
    const int y   = gy & (H - 1);         //  never spans a batch boundary)
    const int scheme = scheme_arr[b];
    const int off = gy * W + (lane << 3); // 8 px per lane

    const float* pA = A + off;
    const float* pB = B + off;
    const float* pF = F + off;
    const bool vm = (y > 0);              // wave-uniform
    const bool vq = (y < H - 2);          // y+2 valid (y is even, <= 510)

    const float4 z4 = make_float4(0.f, 0.f, 0.f, 0.f);

#define LD2(d0_, d1_, p_) do {                                              \
    d0_ = *reinterpret_cast<const float4*>(p_);                             \
    d1_ = *reinterpret_cast<const float4*>((p_) + 4);                       \
} while (0)
#define LDROW(d0_, d1_, p_, v_) do {                                        \
    if (v_) LD2(d0_, d1_, p_); else { d0_ = z4; d1_ = z4; }                 \
} while (0)

    // halo pair for one row (two float4): l_ = col x0-1, r_ = col x0+8
#define HALO(l_, r_, r0_, r1_) do {                                         \
    l_ = __shfl_up((r1_).w, 1, 64);                                         \
    r_ = __shfl_down((r0_).x, 1, 64);                                       \
    if (lane == 0)  l_ = 0.f;                                               \
    if (lane == 63) r_ = 0.f;                                               \
} while (0)

    // Separable sobel over one 6-col half-window (outputs jj = JB_..JB_+3):
    // s[j] = t+2c+q (x-smoothing col sum), d[j] = t-q (y-derivative);
    // gx = s[j+2]-s[j], gy = d[j]+2d[j+1]+d[j+2], sob = |gx|+|gy|.
    // (verified exact vs reference in R7: absmax 0)
#define SOBH(JB_, T0,T1,T2,T3,T4,T5, C0,C1,C2,C3,C4,C5,                     \
             Q0,Q1,Q2,Q3,Q4,Q5, ...) do {                                   \
    const float s_[6] = {(T0) + 2.f*(C0) + (Q0), (T1) + 2.f*(C1) + (Q1),    \
                         (T2) + 2.f*(C2) + (Q2), (T3) + 2.f*(C3) + (Q3),    \
                         (T4) + 2.f*(C4) + (Q4), (T5) + 2.f*(C5) + (Q5)};   \
    const float d_[6] = {(T0) - (Q0), (T1) - (Q1), (T2) - (Q2),             \
                         (T3) - (Q3), (T4) - (Q4), (T5) - (Q5)};            \
    _Pragma("unroll")                                                       \
    for (int j = 0; j < 4; ++j) {                                           \
        const int jj = (JB_) + j; (void)jj;                                 \
        const float gx  = s_[j + 2] - s_[j];                                \
        const float gyv = d_[j] + 2.f * d_[j + 1] + d_[j + 2];              \
        const float sob = fabsf(gx) + fabsf(gyv);                           \
        __VA_ARGS__;                                                        \
    }                                                                       \
} while (0)

    // one output row from rows T=(t0,t1), C=(c0,c1), Q=(q0,q1) with halos
#define SOBROW(JB_, t0,t1,lt,rt, c0_,c1_,lc,rc, q0,q1,lq,rq, ...) do {      \
    SOBH(JB_, lt, (t0).x, (t0).y, (t0).z, (t0).w, (t1).x,                   \
              lc, (c0_).x, (c0_).y, (c0_).z, (c0_).w, (c1_).x,              \
              lq, (q0).x, (q0).y, (q0).z, (q0).w, (q1).x, __VA_ARGS__);     \
    SOBH((JB_) + 4, (t0).w, (t1).x, (t1).y, (t1).z, (t1).w, rt,             \
              (c0_).w, (c1_).x, (c1_).y, (c1_).z, (c1_).w, rc,              \
              (q0).w, (q1).x, (q1).y, (q1).z, (q1).w, rq, __VA_ARGS__);     \
} while (0)

    // per-image phase: rows m=y-1, c=y, d=y+1, q=y+2; output rows y (jj
    // 0..7) and y+1 (jj 8..15)
#define PHASE(P_, ...) do {                                                 \
    float lm, rm, lc, rc, ld, rd, lq, rq;                                   \
    HALO(lm, rm, m0, m1);                                                   \
    HALO(lc, rc, c0, c1);                                                   \
    HALO(ld, rd, d0, d1);                                                   \
    HALO(lq, rq, q0, q1);                                                   \
    SOBROW(0, m0, m1, lm, rm, c0, c1, lc, rc, d0, d1, ld, rd, __VA_ARGS__); \
    SOBROW(8, c0, c1, lc, rc, d0, d1, ld, rd, q0, q1, lq, rq, __VA_ARGS__); \
} while (0)

    float4 m0, m1, c0, c1, d0, d1, q0, q1;  // current image's 4 rows
    float4 aC[4], bC[4];                    // saved A/B center rows (y,y+1)
    float  sobM[16];
    float  acc = 0.f;

    // ---- phase A ----
    LDROW(m0, m1, pA - W, vm);
    LD2(c0, c1, pA);
    LD2(d0, d1, pA + W);
    LDROW(q0, q1, pA + 2 * W, vq);
    PHASE(A, sobM[jj] = sob);
    aC[0] = c0; aC[1] = c1; aC[2] = d0; aC[3] = d1;

    // ---- phase B ----
    LDROW(m0, m1, pB - W, vm);
    LD2(c0, c1, pB);
    LD2(d0, d1, pB + W);
    LDROW(q0, q1, pB + 2 * W, vq);
    PHASE(B, sobM[jj] = fmaxf(sobM[jj], sob));
    bC[0] = c0; bC[1] = c1; bC[2] = d0; bC[3] = d1;

    // ---- phase F: loads, l_loss (frees aC/bC), then sobel F ----
    LDROW(m0, m1, pF - W, vm);
    LD2(c0, c1, pF);
    LD2(d0, d1, pF + W);
    LDROW(q0, q1, pF + 2 * W, vq);
    {
        const float4 fC[4] = {c0, c1, d0, d1};
#pragma unroll
        for (int k = 0; k < 4; ++k) {
            const float av[4] = {aC[k].x, aC[k].y, aC[k].z, aC[k].w};
            const float bv[4] = {bC[k].x, bC[k].y, bC[k].z, bC[k].w};
            const float fv[4] = {fC[k].x, fC[k].y, fC[k].z, fC[k].w};
#pragma unroll
            for (int j = 0; j < 4; ++j) {
                const float ab = (scheme == 0) ? 0.5f * (av[j] + bv[j])
                               : (scheme == 1) ? fmaxf(av[j], bv[j])
                               : 0.f;
                acc += fabsf(ab - fv[j]);
            }
        }
    }
    PHASE(F, acc += fabsf(sob - sobM[jj]));

#undef LD2
#undef LDROW
#undef HALO
#undef SOBH
#undef SOBROW
#undef PHASE

    // ---- reduction: 64-lane shuffle, cross-wave via LDS, one plain store
    // per block to a distinct workspace slot (parallel drain, no atomics).
#pragma unroll
    for (int offp = 32; offp > 0; offp >>= 1)
        acc += __shfl_down(acc, offp, 64);
    if (lane == 0) red[ty] = acc;
    __syncthreads();
    if (t == 0) {
        const float s = red[0] + red[1] + red[2] + red[3];
        if (USE_PARTIALS)
            sink[bid] = s;
        else
            atomicAdd(sink, s * (1.0f / (float)N_TOT)); // fallback path
    }
}

// 1-block finish: sum NBLOCKS=2048 partials (256 threads x 2 float4),
// scale by 1/N, write the scalar. Kernel boundary on the stream guarantees
// visibility of kernel1's plain stores.
__global__ __launch_bounds__(256)
void fusion_finish(const float* __restrict__ partials, float* __restrict__ out)
{
    __shared__ float red[4];
    const int t    = threadIdx.x;
    const int lane = t & 63;
    const int ty   = t >> 6;

    float s = 0.f;
#pragma unroll
    for (int k = 0; k < 2; ++k) {
        const float4 p = reinterpret_cast<const float4*>(partials)[t + 256 * k];
        s += (p.x + p.y) + (p.z + p.w);
    }
#pragma unroll
    for (int off = 32; off > 0; off >>= 1)
        s += __shfl_down(s, off, 64);
    if (lane == 0) red[ty] = s;
    __syncthreads();
    if (t == 0)
        out[0] = (red[0] + red[1] + red[2] + red[3]) * (1.0f / (float)N_TOT);
}

extern "C" void kernel_launch(void* const* d_in, const int* in_sizes, int n_in,
                              void* d_out, int out_size, void* d_ws, size_t ws_size,
                              hipStream_t stream)
{
    const float* A = (const float*)d_in[0];
    const float* B = (const float*)d_in[1];
    const float* F = (const float*)d_in[2];
    const int* scheme = (const int*)d_in[3];
    float* out = (float*)d_out;

    if (d_ws != nullptr && ws_size >= WS_FLOATS * sizeof(float)) {
        float* partials = (float*)d_ws;   // 8 KB, 16B-aligned
        fusion_loss_kernel<true><<<dim3(NBLOCKS), dim3(256), 0, stream>>>(
            A, B, F, scheme, partials);
        fusion_finish<<<dim3(1), dim3(256), 0, stream>>>(partials, out);
    } else {
        // Fallback: atomic path (d_out poisoned -> zero it).
        hipMemsetAsync(out, 0, sizeof(float), stream);
        fusion_loss_kernel<false><<<dim3(NBLOCKS), dim3(256), 0, stream>>>(
            A, B, F, scheme, out);
    }
}